// Round 5
// baseline (607.837 us; speedup 1.0000x reference)
//
#include <hip/hip_runtime.h>
#include <hip/hip_bf16.h>

// Problem constants (CausalMultiHeadSelfAttention): B=4, S=2048, E=1024, H=16, D=64
#define E_DIM 1024
#define N_HEADS 16
#define HEAD_D 64
#define BATCH 4
#define SEQ 2048
#define M_ROWS (BATCH * SEQ)  // 8192

typedef __attribute__((ext_vector_type(4))) float f32x4;
typedef __attribute__((ext_vector_type(8))) short s16x8;  // 8 bf16 in 4 VGPRs

__device__ __forceinline__ unsigned short f2b(float f) {
  union { float f; unsigned u; } v; v.f = f;
  unsigned r = v.u + 0x7fffu + ((v.u >> 16) & 1u);  // RNE
  return (unsigned short)(r >> 16);
}

__device__ __forceinline__ unsigned packbf2(float lo, float hi) {
  union { __hip_bfloat162 h; unsigned u; } p;
  p.h = __float22bfloat162_rn(float2{lo, hi});  // v_cvt_pk_bf16_f32
  return p.u;
}

__device__ __forceinline__ void gld16(const void* g, void* l) {
  __builtin_amdgcn_global_load_lds(
      (__attribute__((address_space(1))) void*)(g),
      (__attribute__((address_space(3))) void*)(l), 16, 0, 0);
}

// ---------------- cast x (fp32 -> bf16), vectorized ----------------
__global__ __launch_bounds__(256) void cast_x_kernel(const float* __restrict__ in,
                                                     unsigned short* __restrict__ out,
                                                     int n4) {
  int i = blockIdx.x * 256 + threadIdx.x;
  const int stride = gridDim.x * 256;
  for (; i < n4; i += stride) {
    float4 v = ((const float4*)in)[i];
    ushort4 o;
    o.x = f2b(v.x); o.y = f2b(v.y); o.z = f2b(v.z); o.w = f2b(v.w);
    ((ushort4*)out)[i] = o;
  }
}

// ---------------- weight transpose+cast: W[K][N] fp32 -> WT[N][K] bf16 ----------------
__global__ __launch_bounds__(256) void wtrans_kernel(const float* __restrict__ W,
                                                     unsigned short* __restrict__ WT) {
  __shared__ float t[64][65];
  const int k0 = blockIdx.x * 64, n0 = blockIdx.y * 64;
  const int tid = threadIdx.x;
  const int rr = tid >> 4, cc = (tid & 15) * 4;
  for (int p = 0; p < 4; ++p) {
    int row = p * 16 + rr;
    float4 v = *(const float4*)&W[(size_t)(k0 + row) * E_DIM + n0 + cc];
    t[row][cc] = v.x; t[row][cc + 1] = v.y; t[row][cc + 2] = v.z; t[row][cc + 3] = v.w;
  }
  __syncthreads();
  for (int p = 0; p < 4; ++p) {
    int nrow = p * 16 + rr;
    ushort4 o;
    o.x = f2b(t[cc][nrow]); o.y = f2b(t[cc + 1][nrow]);
    o.z = f2b(t[cc + 2][nrow]); o.w = f2b(t[cc + 3][nrow]);
    *(ushort4*)&WT[(size_t)(n0 + nrow) * E_DIM + k0 + cc] = o;
  }
}

// ---------------- fused QKV GEMM: [8192,1024] x [1024,3072] ----------------
__global__ __launch_bounds__(256) void gemm_qkv(const unsigned short* __restrict__ A,
                                                const unsigned short* __restrict__ BT,
                                                const float* __restrict__ bq,
                                                const float* __restrict__ bk,
                                                const float* __restrict__ bv,
                                                unsigned short* __restrict__ Qb,
                                                unsigned short* __restrict__ Kb,
                                                unsigned short* __restrict__ Vt) {
  __shared__ unsigned short Al[128 * 64];
  __shared__ unsigned short Bl[128 * 64];
  const int K = E_DIM;
  const int tid = threadIdx.x;
  const int lane = tid & 63;
  const int wave = tid >> 6;
  const int wr = wave >> 1, wc = wave & 1;
  const int m0 = blockIdx.x * 128, n0 = blockIdx.y * 128;

  f32x4 acc[4][4] = {};
  const int srow = tid >> 3;
  const int scol = (tid & 7) * 8;
  const int koff_base = (lane >> 4) * 8;
  const int lrow = lane & 15;

  for (int k0 = 0; k0 < K; k0 += 64) {
    for (int p = 0; p < 4; ++p) {
      int row = p * 32 + srow;
      gld16((const void*)(A + (size_t)(m0 + row) * K + k0 + scol),
            (void*)(Al + p * 2048 + wave * 512));
      gld16((const void*)(BT + (size_t)(n0 + row) * K + k0 + scol),
            (void*)(Bl + p * 2048 + wave * 512));
    }
    __syncthreads();
    for (int ks = 0; ks < 2; ++ks) {
      const int koff = ks * 32 + koff_base;
      s16x8 af[4], bf_[4];
      for (int i = 0; i < 4; ++i)
        af[i] = *(const s16x8*)&Al[(wr * 64 + i * 16 + lrow) * 64 + koff];
      for (int j = 0; j < 4; ++j)
        bf_[j] = *(const s16x8*)&Bl[(wc * 64 + j * 16 + lrow) * 64 + koff];
      for (int i = 0; i < 4; ++i)
        for (int j = 0; j < 4; ++j)
          acc[i][j] = __builtin_amdgcn_mfma_f32_16x16x32_bf16(af[i], bf_[j], acc[i][j], 0, 0, 0);
    }
    __syncthreads();
  }

  for (int j = 0; j < 4; ++j) {
    int c = n0 + wc * 64 + j * 16 + lrow;   // global col in [0,3072)
    int proj = c >> 10, cc = c & 1023;
    float bvl = (proj == 0) ? bq[cc] : (proj == 1) ? bk[cc] : bv[cc];
    for (int i = 0; i < 4; ++i) {
      int r0 = m0 + wr * 64 + i * 16 + ((lane >> 4) << 2);
      for (int r = 0; r < 4; ++r) {
        float val = acc[i][j][r] + bvl;
        int m = r0 + r;
        if (proj == 0) {
          Qb[(size_t)m * E_DIM + cc] = f2b(val);
        } else if (proj == 1) {
          Kb[(size_t)m * E_DIM + cc] = f2b(val);
        } else {
          int b = m >> 11, s = m & 2047;
          int h = cc >> 6, d = cc & 63;
          Vt[((size_t)((b * 16 + h) * 64 + d)) * SEQ + s] = f2b(val);
        }
      }
    }
  }
}

// ---------------- plain GEMM (output projection): f32 out ----------------
__global__ __launch_bounds__(256) void gemm_out(const unsigned short* __restrict__ A,
                                                const unsigned short* __restrict__ BT,
                                                const float* __restrict__ bias,
                                                float* __restrict__ C) {
  __shared__ unsigned short Al[128 * 64];
  __shared__ unsigned short Bl[128 * 64];
  const int K = E_DIM, N = E_DIM;
  const int tid = threadIdx.x;
  const int lane = tid & 63;
  const int wave = tid >> 6;
  const int wr = wave >> 1, wc = wave & 1;
  const int m0 = blockIdx.x * 128, n0 = blockIdx.y * 128;

  f32x4 acc[4][4] = {};
  const int srow = tid >> 3;
  const int scol = (tid & 7) * 8;
  const int koff_base = (lane >> 4) * 8;
  const int lrow = lane & 15;

  for (int k0 = 0; k0 < K; k0 += 64) {
    for (int p = 0; p < 4; ++p) {
      int row = p * 32 + srow;
      gld16((const void*)(A + (size_t)(m0 + row) * K + k0 + scol),
            (void*)(Al + p * 2048 + wave * 512));
      gld16((const void*)(BT + (size_t)(n0 + row) * K + k0 + scol),
            (void*)(Bl + p * 2048 + wave * 512));
    }
    __syncthreads();
    for (int ks = 0; ks < 2; ++ks) {
      const int koff = ks * 32 + koff_base;
      s16x8 af[4], bf_[4];
      for (int i = 0; i < 4; ++i)
        af[i] = *(const s16x8*)&Al[(wr * 64 + i * 16 + lrow) * 64 + koff];
      for (int j = 0; j < 4; ++j)
        bf_[j] = *(const s16x8*)&Bl[(wc * 64 + j * 16 + lrow) * 64 + koff];
      for (int i = 0; i < 4; ++i)
        for (int j = 0; j < 4; ++j)
          acc[i][j] = __builtin_amdgcn_mfma_f32_16x16x32_bf16(af[i], bf_[j], acc[i][j], 0, 0, 0);
    }
    __syncthreads();
  }

  for (int j = 0; j < 4; ++j) {
    int col = n0 + wc * 64 + j * 16 + lrow;
    float bvl = bias[col];
    for (int i = 0; i < 4; ++i) {
      int r0 = m0 + wr * 64 + i * 16 + ((lane >> 4) << 2);
      for (int r = 0; r < 4; ++r)
        C[(size_t)(r0 + r) * N + col] = acc[i][j][r] + bvl;
    }
  }
}

// ---------------- causal flash attention v5 (latency attack) ----------------
// v4 algorithm + three latency levers:
//  1) XCD-aware swizzle: 1-D grid, xcd=id&7 owns 8 heads -> K+V (4 MB) fits
//     that XCD's L2; all 16 ip-blocks of a head share one L2.
//  2) K double-buffer prefetch (unroll-by-2, static kfA/kfB -- no runtime
//     array indexing, rule #20): next tile's K loads issue before this tile's
//     compute. V keeps single buffer (used ~400cy after its load).
//  3) launch_bounds(256,3) (cap~170 VGPR) + in-place score mask/scale (-16
//     regs) -> 3 waves/SIMD resident, no spill.
__global__ __launch_bounds__(256, 3) void attn5_kernel(const unsigned short* __restrict__ Qb,
                                                       const unsigned short* __restrict__ Kb,
                                                       const unsigned short* __restrict__ Vt,
                                                       unsigned short* __restrict__ Ob) {
  const int tid = threadIdx.x, lane = tid & 63, wave = tid >> 6;
  // swizzle decode: 1024 blocks = 8 xcd * 8 bh-sub * 16 ip
  const int id = blockIdx.x;
  const int xcd = id & 7;
  const int slot = id >> 3;
  const int bh = (xcd << 3) | (slot >> 4);
  const int ip = slot & 15;  // pair index: chunks ip and 31-ip
  const size_t base = (size_t)(bh >> 4) * SEQ * E_DIM + (size_t)(bh & 15) * HEAD_D;
  const size_t baset = (size_t)bh * HEAD_D * SEQ;
  const int lq = lane & 15, lg = lane >> 4;

  const int row_lo = ip * 64 + wave * 16 + lq;         // qi=0 q-row
  const int row_hi = (31 - ip) * 64 + wave * 16 + lq;  // qi=1 q-row

  // Q B-frags (row = lane&15, d-run = lg*8 / 32+lg*8)
  s16x8 qf0[2], qf1[2];
  {
    const unsigned short* p0 = Qb + base + (size_t)row_lo * E_DIM + lg * 8;
    qf0[0] = *(const s16x8*)p0; qf0[1] = *(const s16x8*)(p0 + 32);
    const unsigned short* p1 = Qb + base + (size_t)row_hi * E_DIM + lg * 8;
    qf1[0] = *(const s16x8*)p1; qf1[1] = *(const s16x8*)(p1 + 32);
  }

  const short onebf = (short)0x3F80;
  const s16x8 ones = {onebf, onebf, onebf, onebf, onebf, onebf, onebf, onebf};

  float m0r = -1e30f, m1r = -1e30f;
  f32x4 o0[4] = {}, o1[4] = {};
  f32x4 l0 = {}, l1 = {};
  const float scale2 = 0.125f * 1.44269504089f;  // exp2 domain
  const int ntm1 = 31 - ip;
  const bool hi5 = (lane & 32) != 0, hi4 = (lane & 16) != 0;

  s16x8 vf[4][2];

  auto loadK = [&](s16x8 (&kf)[4][2], int kk0) {
#pragma unroll
    for (int kb = 0; kb < 4; ++kb) {
      const unsigned short* kp = Kb + base + (size_t)(kk0 + kb * 16 + lq) * E_DIM + lg * 8;
      kf[kb][0] = *(const s16x8*)kp;
      kf[kb][1] = *(const s16x8*)(kp + 32);
    }
  };
  auto loadV = [&](int kk0) {
#pragma unroll
    for (int db = 0; db < 4; ++db) {
      const unsigned short* vp = Vt + baset + (size_t)(db * 16 + lq) * SEQ + kk0 + lg * 8;
      vf[db][0] = *(const s16x8*)vp;
      vf[db][1] = *(const s16x8*)(vp + 32);
    }
  };

  auto process = [&](f32x4 (&sv)[4], int qrow, bool diag, float& mreg,
                     f32x4 (&oacc)[4], f32x4& lacc, int kk0) {
    // scale + causal mask, in place (keeps register pressure down)
#pragma unroll
    for (int kb = 0; kb < 4; ++kb)
#pragma unroll
      for (int r = 0; r < 4; ++r) {
        float v = sv[kb][r] * scale2;
        if (diag) {
          int kk = kk0 + kb * 16 + lg * 4 + r;
          if (kk > qrow) v = -1e30f;
        }
        sv[kb][r] = v;
      }
    // row max: 15 in-register + 2 cross-group shuffles
    float mx = sv[0][0];
#pragma unroll
    for (int kb = 0; kb < 4; ++kb)
#pragma unroll
      for (int r = 0; r < 4; ++r) mx = fmaxf(mx, sv[kb][r]);
    mx = fmaxf(mx, __shfl_xor(mx, 16, 64));
    mx = fmaxf(mx, __shfl_xor(mx, 32, 64));
    float mn = fmaxf(mreg, mx);
    float corr = __builtin_amdgcn_exp2f(mreg - mn);
    mreg = mn;
    // exp + pack pairs (bf16x2 words) c[kb][rp]
    unsigned c[4][2];
#pragma unroll
    for (int kb = 0; kb < 4; ++kb)
#pragma unroll
      for (int rp = 0; rp < 2; ++rp) {
        float plo = __builtin_amdgcn_exp2f(sv[kb][2 * rp] - mn);
        float phi = __builtin_amdgcn_exp2f(sv[kb][2 * rp + 1] - mn);
        c[kb][rp] = packbf2(plo, phi);
      }
    // butterfly B1: swap lane-bit5 <-> reg-bit kb0
#pragma unroll
    for (int k1 = 0; k1 < 2; ++k1)
#pragma unroll
      for (int rp = 0; rp < 2; ++rp) {
        unsigned a = c[2 * k1][rp], b = c[2 * k1 + 1][rp];
        unsigned x = hi5 ? a : b;
        x = __shfl_xor(x, 32, 64);
        c[2 * k1][rp] = hi5 ? x : a;
        c[2 * k1 + 1][rp] = hi5 ? b : x;
      }
    // butterfly B2: swap lane-bit4 <-> reg-bit (now s1)
#pragma unroll
    for (int k1 = 0; k1 < 2; ++k1)
#pragma unroll
      for (int rp = 0; rp < 2; ++rp) {
        unsigned a = c[2 * k1][rp], b = c[2 * k1 + 1][rp];
        unsigned x = hi4 ? a : b;
        x = __shfl_xor(x, 16, 64);
        c[2 * k1][rp] = hi4 ? x : a;
        c[2 * k1 + 1][rp] = hi4 ? b : x;
      }
    // rescale accumulators
#pragma unroll
    for (int db = 0; db < 4; ++db) oacc[db] = oacc[db] * corr;
    lacc = lacc * corr;
    // PV + row-sum
#pragma unroll
    for (int ks = 0; ks < 2; ++ks) {
      union { unsigned w[4]; s16x8 v; } pu;
      pu.w[0] = c[2 * ks][0]; pu.w[1] = c[2 * ks][1];
      pu.w[2] = c[2 * ks + 1][0]; pu.w[3] = c[2 * ks + 1][1];
      lacc = __builtin_amdgcn_mfma_f32_16x16x32_bf16(ones, pu.v, lacc, 0, 0, 0);
#pragma unroll
      for (int db = 0; db < 4; ++db)
        oacc[db] = __builtin_amdgcn_mfma_f32_16x16x32_bf16(vf[db][ks], pu.v, oacc[db], 0, 0, 0);
    }
  };

  auto tile = [&](s16x8 (&kf)[4][2], int tt) {
    const int kk0 = tt * 64;
    {
      f32x4 s1v[4] = {};
#pragma unroll
      for (int kb = 0; kb < 4; ++kb) {
        s1v[kb] = __builtin_amdgcn_mfma_f32_16x16x32_bf16(kf[kb][0], qf1[0], s1v[kb], 0, 0, 0);
        s1v[kb] = __builtin_amdgcn_mfma_f32_16x16x32_bf16(kf[kb][1], qf1[1], s1v[kb], 0, 0, 0);
      }
      process(s1v, row_hi, tt == ntm1, m1r, o1, l1, kk0);
    }
    if (tt <= ip) {
      f32x4 s0v[4] = {};
#pragma unroll
      for (int kb = 0; kb < 4; ++kb) {
        s0v[kb] = __builtin_amdgcn_mfma_f32_16x16x32_bf16(kf[kb][0], qf0[0], s0v[kb], 0, 0, 0);
        s0v[kb] = __builtin_amdgcn_mfma_f32_16x16x32_bf16(kf[kb][1], qf0[1], s0v[kb], 0, 0, 0);
      }
      process(s0v, row_lo, tt == ip, m0r, o0, l0, kk0);
    }
  };

  // unroll-by-2 main loop with K double-buffer (static bufs kfA/kfB)
  s16x8 kfA[4][2], kfB[4][2];
  loadK(kfA, 0);
  int t = 0;
  for (;;) {
    if (t + 1 <= ntm1) loadK(kfB, (t + 1) * 64);  // prefetch next K
    loadV(t * 64);
    tile(kfA, t);
    if (t + 1 > ntm1) break;
    if (t + 2 <= ntm1) loadK(kfA, (t + 2) * 64);  // prefetch next-next K
    loadV((t + 1) * 64);
    tile(kfB, t + 1);
    if (t + 2 > ntm1) break;
    t += 2;
  }

  // epilogue: O[q][d] = oacc/l; lane holds q=lq(+chunk), d = db*16+lg*4+r
  {
    float inv0 = 1.0f / l0[0], inv1 = 1.0f / l1[0];
#pragma unroll
    for (int db = 0; db < 4; ++db) {
      ushort4 w0, w1;
      w0.x = f2b(o0[db][0] * inv0); w0.y = f2b(o0[db][1] * inv0);
      w0.z = f2b(o0[db][2] * inv0); w0.w = f2b(o0[db][3] * inv0);
      w1.x = f2b(o1[db][0] * inv1); w1.y = f2b(o1[db][1] * inv1);
      w1.z = f2b(o1[db][2] * inv1); w1.w = f2b(o1[db][3] * inv1);
      *(ushort4*)&Ob[base + (size_t)row_lo * E_DIM + db * 16 + lg * 4] = w0;
      *(ushort4*)&Ob[base + (size_t)row_hi * E_DIM + db * 16 + lg * 4] = w1;
    }
  }
}

extern "C" void kernel_launch(void* const* d_in, const int* in_sizes, int n_in,
                              void* d_out, int out_size, void* d_ws, size_t ws_size,
                              hipStream_t stream) {
  const float* x    = (const float*)d_in[0];
  const float* wq_w = (const float*)d_in[1];
  const float* wq_b = (const float*)d_in[2];
  const float* wk_w = (const float*)d_in[3];
  const float* wk_b = (const float*)d_in[4];
  const float* wv_w = (const float*)d_in[5];
  const float* wv_b = (const float*)d_in[6];
  const float* wo_w = (const float*)d_in[7];
  const float* wo_b = (const float*)d_in[8];
  float* out = (float*)d_out;

  const size_t XE = (size_t)M_ROWS * E_DIM;
  const size_t WE = (size_t)E_DIM * E_DIM;
  char* ws = (char*)d_ws;
  unsigned short* xb    = (unsigned short*)ws; ws += XE * 2;
  unsigned short* wqkvT = (unsigned short*)ws; ws += 3 * WE * 2;  // [3072][1024]
  unsigned short* woT   = (unsigned short*)ws; ws += WE * 2;
  unsigned short* Qb    = (unsigned short*)ws; ws += XE * 2;
  unsigned short* Kb    = (unsigned short*)ws; ws += XE * 2;
  unsigned short* Vt    = (unsigned short*)ws; ws += XE * 2;  // [bh*64+d][s]
  unsigned short* Ao    = (unsigned short*)ws; ws += XE * 2;

  cast_x_kernel<<<2048, 256, 0, stream>>>(x, xb, (int)(XE / 4));
  dim3 tg(E_DIM / 64, E_DIM / 64);
  wtrans_kernel<<<tg, 256, 0, stream>>>(wq_w, wqkvT);
  wtrans_kernel<<<tg, 256, 0, stream>>>(wk_w, wqkvT + WE);
  wtrans_kernel<<<tg, 256, 0, stream>>>(wv_w, wqkvT + 2 * WE);
  wtrans_kernel<<<tg, 256, 0, stream>>>(wo_w, woT);

  gemm_qkv<<<dim3(M_ROWS / 128, 3072 / 128), 256, 0, stream>>>(
      xb, wqkvT, wq_b, wk_b, wv_b, Qb, Kb, Vt);

  attn5_kernel<<<1024, 256, 0, stream>>>(Qb, Kb, Vt, Ao);

  gemm_out<<<dim3(M_ROWS / 128, E_DIM / 128), 256, 0, stream>>>(Ao, woT, wo_b, out);
}

// Round 6
// 229.430 us; speedup vs baseline: 2.6493x; 2.6493x over previous
//
#include <hip/hip_runtime.h>
#include <hip/hip_bf16.h>

// Problem constants (CausalMultiHeadSelfAttention): B=4, S=2048, E=1024, H=16, D=64
#define E_DIM 1024
#define N_HEADS 16
#define HEAD_D 64
#define BATCH 4
#define SEQ 2048
#define M_ROWS (BATCH * SEQ)  // 8192

typedef __attribute__((ext_vector_type(4))) float f32x4;
typedef __attribute__((ext_vector_type(8))) short s16x8;  // 8 bf16 in 4 VGPRs

__device__ __forceinline__ unsigned short f2b(float f) {
  union { float f; unsigned u; } v; v.f = f;
  unsigned r = v.u + 0x7fffu + ((v.u >> 16) & 1u);  // RNE
  return (unsigned short)(r >> 16);
}

__device__ __forceinline__ unsigned packbf2(float lo, float hi) {
  union { __hip_bfloat162 h; unsigned u; } p;
  p.h = __float22bfloat162_rn(float2{lo, hi});  // v_cvt_pk_bf16_f32
  return p.u;
}

__device__ __forceinline__ void gld16(const void* g, void* l) {
  __builtin_amdgcn_global_load_lds(
      (__attribute__((address_space(1))) void*)(g),
      (__attribute__((address_space(3))) void*)(l), 16, 0, 0);
}

// ---------------- cast x (fp32 -> bf16), vectorized ----------------
__global__ __launch_bounds__(256) void cast_x_kernel(const float* __restrict__ in,
                                                     unsigned short* __restrict__ out,
                                                     int n4) {
  int i = blockIdx.x * 256 + threadIdx.x;
  const int stride = gridDim.x * 256;
  for (; i < n4; i += stride) {
    float4 v = ((const float4*)in)[i];
    ushort4 o;
    o.x = f2b(v.x); o.y = f2b(v.y); o.z = f2b(v.z); o.w = f2b(v.w);
    ((ushort4*)out)[i] = o;
  }
}

// ---------------- weight transpose+cast: W[K][N] fp32 -> WT[N][K] bf16 ----------------
__global__ __launch_bounds__(256) void wtrans_kernel(const float* __restrict__ W,
                                                     unsigned short* __restrict__ WT) {
  __shared__ float t[64][65];
  const int k0 = blockIdx.x * 64, n0 = blockIdx.y * 64;
  const int tid = threadIdx.x;
  const int rr = tid >> 4, cc = (tid & 15) * 4;
  for (int p = 0; p < 4; ++p) {
    int row = p * 16 + rr;
    float4 v = *(const float4*)&W[(size_t)(k0 + row) * E_DIM + n0 + cc];
    t[row][cc] = v.x; t[row][cc + 1] = v.y; t[row][cc + 2] = v.z; t[row][cc + 3] = v.w;
  }
  __syncthreads();
  for (int p = 0; p < 4; ++p) {
    int nrow = p * 16 + rr;
    ushort4 o;
    o.x = f2b(t[cc][nrow]); o.y = f2b(t[cc + 1][nrow]);
    o.z = f2b(t[cc + 2][nrow]); o.w = f2b(t[cc + 3][nrow]);
    *(ushort4*)&WT[(size_t)(n0 + nrow) * E_DIM + k0 + cc] = o;
  }
}

// ---------------- fused QKV GEMM: [8192,1024] x [1024,3072] ----------------
__global__ __launch_bounds__(256) void gemm_qkv(const unsigned short* __restrict__ A,
                                                const unsigned short* __restrict__ BT,
                                                const float* __restrict__ bq,
                                                const float* __restrict__ bk,
                                                const float* __restrict__ bv,
                                                unsigned short* __restrict__ Qb,
                                                unsigned short* __restrict__ Kb,
                                                unsigned short* __restrict__ Vt) {
  __shared__ unsigned short Al[128 * 64];
  __shared__ unsigned short Bl[128 * 64];
  const int K = E_DIM;
  const int tid = threadIdx.x;
  const int lane = tid & 63;
  const int wave = tid >> 6;
  const int wr = wave >> 1, wc = wave & 1;
  const int m0 = blockIdx.x * 128, n0 = blockIdx.y * 128;

  f32x4 acc[4][4] = {};
  const int srow = tid >> 3;
  const int scol = (tid & 7) * 8;
  const int koff_base = (lane >> 4) * 8;
  const int lrow = lane & 15;

  for (int k0 = 0; k0 < K; k0 += 64) {
    for (int p = 0; p < 4; ++p) {
      int row = p * 32 + srow;
      gld16((const void*)(A + (size_t)(m0 + row) * K + k0 + scol),
            (void*)(Al + p * 2048 + wave * 512));
      gld16((const void*)(BT + (size_t)(n0 + row) * K + k0 + scol),
            (void*)(Bl + p * 2048 + wave * 512));
    }
    __syncthreads();
    for (int ks = 0; ks < 2; ++ks) {
      const int koff = ks * 32 + koff_base;
      s16x8 af[4], bf_[4];
      for (int i = 0; i < 4; ++i)
        af[i] = *(const s16x8*)&Al[(wr * 64 + i * 16 + lrow) * 64 + koff];
      for (int j = 0; j < 4; ++j)
        bf_[j] = *(const s16x8*)&Bl[(wc * 64 + j * 16 + lrow) * 64 + koff];
      for (int i = 0; i < 4; ++i)
        for (int j = 0; j < 4; ++j)
          acc[i][j] = __builtin_amdgcn_mfma_f32_16x16x32_bf16(af[i], bf_[j], acc[i][j], 0, 0, 0);
    }
    __syncthreads();
  }

  for (int j = 0; j < 4; ++j) {
    int c = n0 + wc * 64 + j * 16 + lrow;   // global col in [0,3072)
    int proj = c >> 10, cc = c & 1023;
    float bvl = (proj == 0) ? bq[cc] : (proj == 1) ? bk[cc] : bv[cc];
    for (int i = 0; i < 4; ++i) {
      int r0 = m0 + wr * 64 + i * 16 + ((lane >> 4) << 2);
      for (int r = 0; r < 4; ++r) {
        float val = acc[i][j][r] + bvl;
        int m = r0 + r;
        if (proj == 0) {
          Qb[(size_t)m * E_DIM + cc] = f2b(val);
        } else if (proj == 1) {
          Kb[(size_t)m * E_DIM + cc] = f2b(val);
        } else {
          int b = m >> 11, s = m & 2047;
          int h = cc >> 6, d = cc & 63;
          Vt[((size_t)((b * 16 + h) * 64 + d)) * SEQ + s] = f2b(val);
        }
      }
    }
  }
}

// ---------------- plain GEMM (output projection): f32 out ----------------
__global__ __launch_bounds__(256) void gemm_out(const unsigned short* __restrict__ A,
                                                const unsigned short* __restrict__ BT,
                                                const float* __restrict__ bias,
                                                float* __restrict__ C) {
  __shared__ unsigned short Al[128 * 64];
  __shared__ unsigned short Bl[128 * 64];
  const int K = E_DIM, N = E_DIM;
  const int tid = threadIdx.x;
  const int lane = tid & 63;
  const int wave = tid >> 6;
  const int wr = wave >> 1, wc = wave & 1;
  const int m0 = blockIdx.x * 128, n0 = blockIdx.y * 128;

  f32x4 acc[4][4] = {};
  const int srow = tid >> 3;
  const int scol = (tid & 7) * 8;
  const int koff_base = (lane >> 4) * 8;
  const int lrow = lane & 15;

  for (int k0 = 0; k0 < K; k0 += 64) {
    for (int p = 0; p < 4; ++p) {
      int row = p * 32 + srow;
      gld16((const void*)(A + (size_t)(m0 + row) * K + k0 + scol),
            (void*)(Al + p * 2048 + wave * 512));
      gld16((const void*)(BT + (size_t)(n0 + row) * K + k0 + scol),
            (void*)(Bl + p * 2048 + wave * 512));
    }
    __syncthreads();
    for (int ks = 0; ks < 2; ++ks) {
      const int koff = ks * 32 + koff_base;
      s16x8 af[4], bf_[4];
      for (int i = 0; i < 4; ++i)
        af[i] = *(const s16x8*)&Al[(wr * 64 + i * 16 + lrow) * 64 + koff];
      for (int j = 0; j < 4; ++j)
        bf_[j] = *(const s16x8*)&Bl[(wc * 64 + j * 16 + lrow) * 64 + koff];
      for (int i = 0; i < 4; ++i)
        for (int j = 0; j < 4; ++j)
          acc[i][j] = __builtin_amdgcn_mfma_f32_16x16x32_bf16(af[i], bf_[j], acc[i][j], 0, 0, 0);
    }
    __syncthreads();
  }

  for (int j = 0; j < 4; ++j) {
    int col = n0 + wc * 64 + j * 16 + lrow;
    float bvl = bias[col];
    for (int i = 0; i < 4; ++i) {
      int r0 = m0 + wr * 64 + i * 16 + ((lane >> 4) << 2);
      for (int r = 0; r < 4; ++r)
        C[(size_t)(r0 + r) * N + col] = acc[i][j][r] + bvl;
    }
  }
}

// ---------------- causal flash attention v6 (LDS-staged, double-buffered) ----------------
// attn4's spill-free compute schedule + block-cooperative K/V LDS staging:
//  - per 64-key tile, 256 threads stage K(8KB)+V(8KB) via global_load_lds,
//    tile t+1's stage issued BEFORE tile t's compute (latency hidden).
//  - XOR swizzle byte^=((row&7)<<4): pre-swizzled global source (linear LDS
//    dest, rule #21) + swizzled ds_read -> conflict-free fragment reads.
//  - single __syncthreads per tile (implicit vmcnt/lgkm drain) = T3-minimal.
//  - XCD swizzle: 8 heads per XCD -> K+V (4MB) fits one L2.
__global__ __launch_bounds__(256, 2) void attn6_kernel(const unsigned short* __restrict__ Qb,
                                                       const unsigned short* __restrict__ Kb,
                                                       const unsigned short* __restrict__ Vt,
                                                       unsigned short* __restrict__ Ob) {
  __shared__ unsigned short Kl[2][4096];  // 8KB per buf: [row 0..63][col 0..63] swizzled
  __shared__ unsigned short Vl[2][4096];  // 8KB per buf: [d 0..63][k 0..63] swizzled

  const int tid = threadIdx.x, lane = tid & 63, wave = tid >> 6;
  // XCD swizzle: 1024 blocks = 8 xcd * 8 heads * 16 ip
  const int id = blockIdx.x;
  const int xcd = id & 7;
  const int slot = id >> 3;
  const int bh = (xcd << 3) | (slot >> 4);
  const int ip = slot & 15;  // pair index: chunks ip and 31-ip
  const size_t base = (size_t)(bh >> 4) * SEQ * E_DIM + (size_t)(bh & 15) * HEAD_D;
  const size_t baset = (size_t)bh * HEAD_D * SEQ;
  const int lq = lane & 15, lg = lane >> 4;

  const int row_lo = ip * 64 + wave * 16 + lq;         // qi=0 q-row
  const int row_hi = (31 - ip) * 64 + wave * 16 + lq;  // qi=1 q-row

  // Q B-frags (row = lane&15, d-run = lg*8 / 32+lg*8)
  s16x8 qf0[2], qf1[2];
  {
    const unsigned short* p0 = Qb + base + (size_t)row_lo * E_DIM + lg * 8;
    qf0[0] = *(const s16x8*)p0; qf0[1] = *(const s16x8*)(p0 + 32);
    const unsigned short* p1 = Qb + base + (size_t)row_hi * E_DIM + lg * 8;
    qf1[0] = *(const s16x8*)p1; qf1[1] = *(const s16x8*)(p1 + 32);
  }

  const short onebf = (short)0x3F80;
  const s16x8 ones = {onebf, onebf, onebf, onebf, onebf, onebf, onebf, onebf};

  float m0r = -1e30f, m1r = -1e30f;
  f32x4 o0[4] = {}, o1[4] = {};
  f32x4 l0 = {}, l1 = {};
  const float scale2 = 0.125f * 1.44269504089f;  // exp2 domain
  const int ntm1 = 31 - ip;
  const bool hi5 = (lane & 32) != 0, hi4 = (lane & 16) != 0;

  // ---- staging: pre-swizzled global source, linear LDS dest ----
  // LDS physical byte o holds logical tile byte o ^ ((row&7)<<4), row = o>>7.
  const int o0b = tid << 4;            // pass 0 byte offset (0..4095)
  const int o1b = 4096 + (tid << 4);   // pass 1 byte offset (4096..8191)
  const int r0s = o0b >> 7, r1s = o1b >> 7;
  const int c0s = ((o0b ^ ((r0s & 7) << 4)) & 127) >> 1;  // source col elem
  const int c1s = ((o1b ^ ((r1s & 7) << 4)) & 127) >> 1;
  // wave-uniform LDS dest bases (HW adds lane*16)
  const int dst0 = wave << 10;           // pass 0: wave*1024 bytes
  const int dst1 = 4096 + (wave << 10);  // pass 1

  auto stage = [&](int buf, int k0) {
    gld16((const void*)(Kb + base + (size_t)(k0 + r0s) * E_DIM + c0s),
          (void*)((char*)&Kl[buf][0] + dst0));
    gld16((const void*)(Kb + base + (size_t)(k0 + r1s) * E_DIM + c1s),
          (void*)((char*)&Kl[buf][0] + dst1));
    gld16((const void*)(Vt + baset + (size_t)r0s * SEQ + k0 + c0s),
          (void*)((char*)&Vl[buf][0] + dst0));
    gld16((const void*)(Vt + baset + (size_t)r1s * SEQ + k0 + c1s),
          (void*)((char*)&Vl[buf][0] + dst1));
  };

  const int swz = (lq & 7) << 4;  // read-side XOR (row&7 == lq&7 for our rows)

  auto process = [&](f32x4 (&sv)[4], int qrow, bool diag, float& mreg,
                     f32x4 (&oacc)[4], f32x4& lacc, int kk0, s16x8 (&vf)[4][2]) {
#pragma unroll
    for (int kb = 0; kb < 4; ++kb)
#pragma unroll
      for (int r = 0; r < 4; ++r) {
        float v = sv[kb][r] * scale2;
        if (diag) {
          int kk = kk0 + kb * 16 + lg * 4 + r;
          if (kk > qrow) v = -1e30f;
        }
        sv[kb][r] = v;
      }
    float mx = sv[0][0];
#pragma unroll
    for (int kb = 0; kb < 4; ++kb)
#pragma unroll
      for (int r = 0; r < 4; ++r) mx = fmaxf(mx, sv[kb][r]);
    mx = fmaxf(mx, __shfl_xor(mx, 16, 64));
    mx = fmaxf(mx, __shfl_xor(mx, 32, 64));
    float mn = fmaxf(mreg, mx);
    float corr = __builtin_amdgcn_exp2f(mreg - mn);
    mreg = mn;
    unsigned c[4][2];
#pragma unroll
    for (int kb = 0; kb < 4; ++kb)
#pragma unroll
      for (int rp = 0; rp < 2; ++rp) {
        float plo = __builtin_amdgcn_exp2f(sv[kb][2 * rp] - mn);
        float phi = __builtin_amdgcn_exp2f(sv[kb][2 * rp + 1] - mn);
        c[kb][rp] = packbf2(plo, phi);
      }
    // butterfly B1: lane-bit5 <-> reg-bit kb0
#pragma unroll
    for (int k1 = 0; k1 < 2; ++k1)
#pragma unroll
      for (int rp = 0; rp < 2; ++rp) {
        unsigned a = c[2 * k1][rp], b = c[2 * k1 + 1][rp];
        unsigned x = hi5 ? a : b;
        x = __shfl_xor(x, 32, 64);
        c[2 * k1][rp] = hi5 ? x : a;
        c[2 * k1 + 1][rp] = hi5 ? b : x;
      }
    // butterfly B2: lane-bit4 <-> reg-bit s1
#pragma unroll
    for (int k1 = 0; k1 < 2; ++k1)
#pragma unroll
      for (int rp = 0; rp < 2; ++rp) {
        unsigned a = c[2 * k1][rp], b = c[2 * k1 + 1][rp];
        unsigned x = hi4 ? a : b;
        x = __shfl_xor(x, 16, 64);
        c[2 * k1][rp] = hi4 ? x : a;
        c[2 * k1 + 1][rp] = hi4 ? b : x;
      }
#pragma unroll
    for (int db = 0; db < 4; ++db) oacc[db] = oacc[db] * corr;
    lacc = lacc * corr;
#pragma unroll
    for (int ks = 0; ks < 2; ++ks) {
      union { unsigned w[4]; s16x8 v; } pu;
      pu.w[0] = c[2 * ks][0]; pu.w[1] = c[2 * ks][1];
      pu.w[2] = c[2 * ks + 1][0]; pu.w[3] = c[2 * ks + 1][1];
      lacc = __builtin_amdgcn_mfma_f32_16x16x32_bf16(ones, pu.v, lacc, 0, 0, 0);
#pragma unroll
      for (int db = 0; db < 4; ++db)
        oacc[db] = __builtin_amdgcn_mfma_f32_16x16x32_bf16(vf[db][ks], pu.v, oacc[db], 0, 0, 0);
    }
  };

  // ---- main loop: 2-phase double buffer ----
  stage(0, 0);
  __syncthreads();  // drains vmcnt -> buf0 ready
  int cur = 0;

  for (int t = 0; t <= ntm1; ++t) {
    if (t < ntm1) stage(cur ^ 1, (t + 1) * 64);  // issue next-tile stage first

    const char* Kc = (const char*)&Kl[cur][0];
    const char* Vc = (const char*)&Vl[cur][0];
    // K fragments from LDS (swizzled read)
    s16x8 kf[4][2];
#pragma unroll
    for (int kb = 0; kb < 4; ++kb)
#pragma unroll
      for (int j = 0; j < 2; ++j)
        kf[kb][j] = *(const s16x8*)(Kc + (((kb * 16 + lq) * 128 + j * 64 + lg * 16) ^ swz));
    // V fragments from LDS (swizzled read)
    s16x8 vf[4][2];
#pragma unroll
    for (int db = 0; db < 4; ++db)
#pragma unroll
      for (int ks = 0; ks < 2; ++ks)
        vf[db][ks] = *(const s16x8*)(Vc + (((db * 16 + lq) * 128 + ks * 64 + lg * 16) ^ swz));

    const int kk0 = t * 64;
    {
      f32x4 s1v[4] = {};
#pragma unroll
      for (int kb = 0; kb < 4; ++kb) {
        s1v[kb] = __builtin_amdgcn_mfma_f32_16x16x32_bf16(kf[kb][0], qf1[0], s1v[kb], 0, 0, 0);
        s1v[kb] = __builtin_amdgcn_mfma_f32_16x16x32_bf16(kf[kb][1], qf1[1], s1v[kb], 0, 0, 0);
      }
      process(s1v, row_hi, t == ntm1, m1r, o1, l1, kk0, vf);
    }
    if (t <= ip) {
      f32x4 s0v[4] = {};
#pragma unroll
      for (int kb = 0; kb < 4; ++kb) {
        s0v[kb] = __builtin_amdgcn_mfma_f32_16x16x32_bf16(kf[kb][0], qf0[0], s0v[kb], 0, 0, 0);
        s0v[kb] = __builtin_amdgcn_mfma_f32_16x16x32_bf16(kf[kb][1], qf0[1], s0v[kb], 0, 0, 0);
      }
      process(s0v, row_lo, t == ip, m0r, o0, l0, kk0, vf);
    }

    __syncthreads();  // next stage complete + all waves done with cur
    cur ^= 1;
  }

  // epilogue: O[q][d] = oacc/l; lane holds q=lq(+chunk), d = db*16+lg*4+r
  {
    float inv0 = 1.0f / l0[0], inv1 = 1.0f / l1[0];
#pragma unroll
    for (int db = 0; db < 4; ++db) {
      ushort4 w0, w1;
      w0.x = f2b(o0[db][0] * inv0); w0.y = f2b(o0[db][1] * inv0);
      w0.z = f2b(o0[db][2] * inv0); w0.w = f2b(o0[db][3] * inv0);
      w1.x = f2b(o1[db][0] * inv1); w1.y = f2b(o1[db][1] * inv1);
      w1.z = f2b(o1[db][2] * inv1); w1.w = f2b(o1[db][3] * inv1);
      *(ushort4*)&Ob[base + (size_t)row_lo * E_DIM + db * 16 + lg * 4] = w0;
      *(ushort4*)&Ob[base + (size_t)row_hi * E_DIM + db * 16 + lg * 4] = w1;
    }
  }
}

extern "C" void kernel_launch(void* const* d_in, const int* in_sizes, int n_in,
                              void* d_out, int out_size, void* d_ws, size_t ws_size,
                              hipStream_t stream) {
  const float* x    = (const float*)d_in[0];
  const float* wq_w = (const float*)d_in[1];
  const float* wq_b = (const float*)d_in[2];
  const float* wk_w = (const float*)d_in[3];
  const float* wk_b = (const float*)d_in[4];
  const float* wv_w = (const float*)d_in[5];
  const float* wv_b = (const float*)d_in[6];
  const float* wo_w = (const float*)d_in[7];
  const float* wo_b = (const float*)d_in[8];
  float* out = (float*)d_out;

  const size_t XE = (size_t)M_ROWS * E_DIM;
  const size_t WE = (size_t)E_DIM * E_DIM;
  char* ws = (char*)d_ws;
  unsigned short* xb    = (unsigned short*)ws; ws += XE * 2;
  unsigned short* wqkvT = (unsigned short*)ws; ws += 3 * WE * 2;  // [3072][1024]
  unsigned short* woT   = (unsigned short*)ws; ws += WE * 2;
  unsigned short* Qb    = (unsigned short*)ws; ws += XE * 2;
  unsigned short* Kb    = (unsigned short*)ws; ws += XE * 2;
  unsigned short* Vt    = (unsigned short*)ws; ws += XE * 2;  // [bh*64+d][s]
  unsigned short* Ao    = (unsigned short*)ws; ws += XE * 2;

  cast_x_kernel<<<2048, 256, 0, stream>>>(x, xb, (int)(XE / 4));
  dim3 tg(E_DIM / 64, E_DIM / 64);
  wtrans_kernel<<<tg, 256, 0, stream>>>(wq_w, wqkvT);
  wtrans_kernel<<<tg, 256, 0, stream>>>(wk_w, wqkvT + WE);
  wtrans_kernel<<<tg, 256, 0, stream>>>(wv_w, wqkvT + 2 * WE);
  wtrans_kernel<<<tg, 256, 0, stream>>>(wo_w, woT);

  gemm_qkv<<<dim3(M_ROWS / 128, 3072 / 128), 256, 0, stream>>>(
      xb, wqkvT, wq_b, wk_b, wv_b, Qb, Kb, Vt);

  attn6_kernel<<<1024, 256, 0, stream>>>(Qb, Kb, Vt, Ao);

  gemm_out<<<dim3(M_ROWS / 128, E_DIM / 128), 256, 0, stream>>>(Ao, woT, wo_b, out);
}

// Round 7
// 206.382 us; speedup vs baseline: 2.9452x; 1.1117x over previous
//
#include <hip/hip_runtime.h>
#include <hip/hip_bf16.h>

// Problem constants (CausalMultiHeadSelfAttention): B=4, S=2048, E=1024, H=16, D=64
#define E_DIM 1024
#define N_HEADS 16
#define HEAD_D 64
#define BATCH 4
#define SEQ 2048
#define M_ROWS (BATCH * SEQ)  // 8192

typedef __attribute__((ext_vector_type(4))) float f32x4;
typedef __attribute__((ext_vector_type(8))) short s16x8;  // 8 bf16 in 4 VGPRs

__device__ __forceinline__ unsigned short f2b(float f) {
  union { float f; unsigned u; } v; v.f = f;
  unsigned r = v.u + 0x7fffu + ((v.u >> 16) & 1u);  // RNE
  return (unsigned short)(r >> 16);
}

__device__ __forceinline__ unsigned packbf2(float lo, float hi) {
  union { __hip_bfloat162 h; unsigned u; } p;
  p.h = __float22bfloat162_rn(float2{lo, hi});  // v_cvt_pk_bf16_f32
  return p.u;
}

__device__ __forceinline__ void gld16(const void* g, void* l) {
  __builtin_amdgcn_global_load_lds(
      (__attribute__((address_space(1))) void*)(g),
      (__attribute__((address_space(3))) void*)(l), 16, 0, 0);
}

// ---------------- cast x (fp32 -> bf16), vectorized ----------------
__global__ __launch_bounds__(256) void cast_x_kernel(const float* __restrict__ in,
                                                     unsigned short* __restrict__ out,
                                                     int n4) {
  int i = blockIdx.x * 256 + threadIdx.x;
  const int stride = gridDim.x * 256;
  for (; i < n4; i += stride) {
    float4 v = ((const float4*)in)[i];
    ushort4 o;
    o.x = f2b(v.x); o.y = f2b(v.y); o.z = f2b(v.z); o.w = f2b(v.w);
    ((ushort4*)out)[i] = o;
  }
}

// ------- fused weight transpose+cast: 4 weights in one launch (grid.z) -------
__global__ __launch_bounds__(256) void wtrans4_kernel(const float* __restrict__ W0,
                                                      const float* __restrict__ W1,
                                                      const float* __restrict__ W2,
                                                      const float* __restrict__ W3,
                                                      unsigned short* __restrict__ D0,
                                                      unsigned short* __restrict__ D1,
                                                      unsigned short* __restrict__ D2,
                                                      unsigned short* __restrict__ D3) {
  const int z = blockIdx.z;
  const float* W = (z == 0) ? W0 : (z == 1) ? W1 : (z == 2) ? W2 : W3;
  unsigned short* WT = (z == 0) ? D0 : (z == 1) ? D1 : (z == 2) ? D2 : D3;
  __shared__ float t[64][65];
  const int k0 = blockIdx.x * 64, n0 = blockIdx.y * 64;
  const int tid = threadIdx.x;
  const int rr = tid >> 4, cc = (tid & 15) * 4;
  for (int p = 0; p < 4; ++p) {
    int row = p * 16 + rr;
    float4 v = *(const float4*)&W[(size_t)(k0 + row) * E_DIM + n0 + cc];
    t[row][cc] = v.x; t[row][cc + 1] = v.y; t[row][cc + 2] = v.z; t[row][cc + 3] = v.w;
  }
  __syncthreads();
  for (int p = 0; p < 4; ++p) {
    int nrow = p * 16 + rr;
    ushort4 o;
    o.x = f2b(t[cc][nrow]); o.y = f2b(t[cc + 1][nrow]);
    o.z = f2b(t[cc + 2][nrow]); o.w = f2b(t[cc + 3][nrow]);
    *(ushort4*)&WT[(size_t)(n0 + nrow) * E_DIM + k0 + cc] = o;
  }
}

// ---------------- fused QKV GEMM: [8192,1024] x [1024,3072] ----------------
// 128x128 tile, BK=64, 4 waves. Double-buffered LDS with issue-early staging
// (attn6 schedule): stage(t+1) issued before compute(t); one barrier/K-step.
// T2 XOR swizzle byte^=((row&7)<<4) via pre-swizzled global source (linear
// LDS dest, rule #21) + swizzled ds_read -> ds_read conflicts ~2-way (free).
__global__ __launch_bounds__(256) void gemm_qkv(const unsigned short* __restrict__ A,
                                                const unsigned short* __restrict__ BT,
                                                const float* __restrict__ bq,
                                                const float* __restrict__ bk,
                                                const float* __restrict__ bv,
                                                unsigned short* __restrict__ Qb,
                                                unsigned short* __restrict__ Kb,
                                                unsigned short* __restrict__ Vt) {
  __shared__ unsigned short Al[2][8192];  // 16 KB per buf: [row 0..127][col 0..63] swizzled
  __shared__ unsigned short Bl[2][8192];
  const int K = E_DIM;
  const int tid = threadIdx.x;
  const int lane = tid & 63;
  const int wave = tid >> 6;
  const int wr = wave >> 1, wc = wave & 1;
  const int m0 = blockIdx.x * 128, n0 = blockIdx.y * 128;
  const int lrow = lane & 15, lg = lane >> 4;

  f32x4 acc[4][4] = {};

  // staging geometry: pass p covers bytes [p*4096, p*4096+4096)
  const int ob = tid << 4;                 // byte offset within pass (0..4095)
  const int dstb = (wave << 10);           // wave-uniform dest base within pass
  int srow[4], scol[4];
#pragma unroll
  for (int p = 0; p < 4; ++p) {
    int o = p * 4096 + ob;
    srow[p] = o >> 7;                                    // 0..127
    scol[p] = ((o ^ ((srow[p] & 7) << 4)) & 127) >> 1;   // source col element
  }

  auto stage = [&](int buf, int k0) {
#pragma unroll
    for (int p = 0; p < 4; ++p) {
      gld16((const void*)(A + (size_t)(m0 + srow[p]) * K + k0 + scol[p]),
            (void*)((char*)&Al[buf][0] + p * 4096 + dstb));
      gld16((const void*)(BT + (size_t)(n0 + srow[p]) * K + k0 + scol[p]),
            (void*)((char*)&Bl[buf][0] + p * 4096 + dstb));
    }
  };

  const int swz = (lrow & 7) << 4;  // read-side XOR

  stage(0, 0);
  __syncthreads();
  int cur = 0;
  const int nt = K / 64;

  for (int t = 0; t < nt; ++t) {
    if (t + 1 < nt) stage(cur ^ 1, (t + 1) * 64);  // issue next-tile stage first
    const char* Ac = (const char*)&Al[cur][0];
    const char* Bc = (const char*)&Bl[cur][0];
#pragma unroll
    for (int ks = 0; ks < 2; ++ks) {
      const int cb = ks * 64 + lg * 16;  // col byte within row
      s16x8 af[4], bf_[4];
#pragma unroll
      for (int i = 0; i < 4; ++i)
        af[i] = *(const s16x8*)(Ac + (((wr * 64 + i * 16 + lrow) * 128 + cb) ^ swz));
#pragma unroll
      for (int j = 0; j < 4; ++j)
        bf_[j] = *(const s16x8*)(Bc + (((wc * 64 + j * 16 + lrow) * 128 + cb) ^ swz));
#pragma unroll
      for (int i = 0; i < 4; ++i)
#pragma unroll
        for (int j = 0; j < 4; ++j)
          acc[i][j] = __builtin_amdgcn_mfma_f32_16x16x32_bf16(af[i], bf_[j], acc[i][j], 0, 0, 0);
    }
    __syncthreads();  // prefetch complete + all waves done with cur
    cur ^= 1;
  }

  for (int j = 0; j < 4; ++j) {
    int c = n0 + wc * 64 + j * 16 + lrow;   // global col in [0,3072)
    int proj = c >> 10, cc = c & 1023;
    float bvl = (proj == 0) ? bq[cc] : (proj == 1) ? bk[cc] : bv[cc];
    for (int i = 0; i < 4; ++i) {
      int r0 = m0 + wr * 64 + i * 16 + (lg << 2);
      for (int r = 0; r < 4; ++r) {
        float val = acc[i][j][r] + bvl;
        int m = r0 + r;
        if (proj == 0) {
          Qb[(size_t)m * E_DIM + cc] = f2b(val);
        } else if (proj == 1) {
          Kb[(size_t)m * E_DIM + cc] = f2b(val);
        } else {
          int b = m >> 11, s = m & 2047;
          int h = cc >> 6, d = cc & 63;
          Vt[((size_t)((b * 16 + h) * 64 + d)) * SEQ + s] = f2b(val);
        }
      }
    }
  }
}

// ---------------- output projection GEMM (f32 out), same schedule ----------------
__global__ __launch_bounds__(256) void gemm_out(const unsigned short* __restrict__ A,
                                                const unsigned short* __restrict__ BT,
                                                const float* __restrict__ bias,
                                                float* __restrict__ C) {
  __shared__ unsigned short Al[2][8192];
  __shared__ unsigned short Bl[2][8192];
  const int K = E_DIM, N = E_DIM;
  const int tid = threadIdx.x;
  const int lane = tid & 63;
  const int wave = tid >> 6;
  const int wr = wave >> 1, wc = wave & 1;
  const int m0 = blockIdx.x * 128, n0 = blockIdx.y * 128;
  const int lrow = lane & 15, lg = lane >> 4;

  f32x4 acc[4][4] = {};

  const int ob = tid << 4;
  const int dstb = (wave << 10);
  int srow[4], scol[4];
#pragma unroll
  for (int p = 0; p < 4; ++p) {
    int o = p * 4096 + ob;
    srow[p] = o >> 7;
    scol[p] = ((o ^ ((srow[p] & 7) << 4)) & 127) >> 1;
  }

  auto stage = [&](int buf, int k0) {
#pragma unroll
    for (int p = 0; p < 4; ++p) {
      gld16((const void*)(A + (size_t)(m0 + srow[p]) * K + k0 + scol[p]),
            (void*)((char*)&Al[buf][0] + p * 4096 + dstb));
      gld16((const void*)(BT + (size_t)(n0 + srow[p]) * K + k0 + scol[p]),
            (void*)((char*)&Bl[buf][0] + p * 4096 + dstb));
    }
  };

  const int swz = (lrow & 7) << 4;

  stage(0, 0);
  __syncthreads();
  int cur = 0;
  const int nt = K / 64;

  for (int t = 0; t < nt; ++t) {
    if (t + 1 < nt) stage(cur ^ 1, (t + 1) * 64);
    const char* Ac = (const char*)&Al[cur][0];
    const char* Bc = (const char*)&Bl[cur][0];
#pragma unroll
    for (int ks = 0; ks < 2; ++ks) {
      const int cb = ks * 64 + lg * 16;
      s16x8 af[4], bf_[4];
#pragma unroll
      for (int i = 0; i < 4; ++i)
        af[i] = *(const s16x8*)(Ac + (((wr * 64 + i * 16 + lrow) * 128 + cb) ^ swz));
#pragma unroll
      for (int j = 0; j < 4; ++j)
        bf_[j] = *(const s16x8*)(Bc + (((wc * 64 + j * 16 + lrow) * 128 + cb) ^ swz));
#pragma unroll
      for (int i = 0; i < 4; ++i)
#pragma unroll
        for (int j = 0; j < 4; ++j)
          acc[i][j] = __builtin_amdgcn_mfma_f32_16x16x32_bf16(af[i], bf_[j], acc[i][j], 0, 0, 0);
    }
    __syncthreads();
    cur ^= 1;
  }

  for (int j = 0; j < 4; ++j) {
    int col = n0 + wc * 64 + j * 16 + lrow;
    float bvl = bias[col];
    for (int i = 0; i < 4; ++i) {
      int r0 = m0 + wr * 64 + i * 16 + (lg << 2);
      for (int r = 0; r < 4; ++r)
        C[(size_t)(r0 + r) * N + col] = acc[i][j][r] + bvl;
    }
  }
}

// ---------------- causal flash attention v6 (LDS-staged, double-buffered) ----------------
__global__ __launch_bounds__(256, 2) void attn6_kernel(const unsigned short* __restrict__ Qb,
                                                       const unsigned short* __restrict__ Kb,
                                                       const unsigned short* __restrict__ Vt,
                                                       unsigned short* __restrict__ Ob) {
  __shared__ unsigned short Kl[2][4096];  // 8KB per buf: [row 0..63][col 0..63] swizzled
  __shared__ unsigned short Vl[2][4096];  // 8KB per buf: [d 0..63][k 0..63] swizzled

  const int tid = threadIdx.x, lane = tid & 63, wave = tid >> 6;
  // XCD swizzle: 1024 blocks = 8 xcd * 8 heads * 16 ip
  const int id = blockIdx.x;
  const int xcd = id & 7;
  const int slot = id >> 3;
  const int bh = (xcd << 3) | (slot >> 4);
  const int ip = slot & 15;  // pair index: chunks ip and 31-ip
  const size_t base = (size_t)(bh >> 4) * SEQ * E_DIM + (size_t)(bh & 15) * HEAD_D;
  const size_t baset = (size_t)bh * HEAD_D * SEQ;
  const int lq = lane & 15, lg = lane >> 4;

  const int row_lo = ip * 64 + wave * 16 + lq;         // qi=0 q-row
  const int row_hi = (31 - ip) * 64 + wave * 16 + lq;  // qi=1 q-row

  s16x8 qf0[2], qf1[2];
  {
    const unsigned short* p0 = Qb + base + (size_t)row_lo * E_DIM + lg * 8;
    qf0[0] = *(const s16x8*)p0; qf0[1] = *(const s16x8*)(p0 + 32);
    const unsigned short* p1 = Qb + base + (size_t)row_hi * E_DIM + lg * 8;
    qf1[0] = *(const s16x8*)p1; qf1[1] = *(const s16x8*)(p1 + 32);
  }

  const short onebf = (short)0x3F80;
  const s16x8 ones = {onebf, onebf, onebf, onebf, onebf, onebf, onebf, onebf};

  float m0r = -1e30f, m1r = -1e30f;
  f32x4 o0[4] = {}, o1[4] = {};
  f32x4 l0 = {}, l1 = {};
  const float scale2 = 0.125f * 1.44269504089f;  // exp2 domain
  const int ntm1 = 31 - ip;
  const bool hi5 = (lane & 32) != 0, hi4 = (lane & 16) != 0;

  const int o0b = tid << 4;
  const int o1b = 4096 + (tid << 4);
  const int r0s = o0b >> 7, r1s = o1b >> 7;
  const int c0s = ((o0b ^ ((r0s & 7) << 4)) & 127) >> 1;
  const int c1s = ((o1b ^ ((r1s & 7) << 4)) & 127) >> 1;
  const int dst0 = wave << 10;
  const int dst1 = 4096 + (wave << 10);

  auto stage = [&](int buf, int k0) {
    gld16((const void*)(Kb + base + (size_t)(k0 + r0s) * E_DIM + c0s),
          (void*)((char*)&Kl[buf][0] + dst0));
    gld16((const void*)(Kb + base + (size_t)(k0 + r1s) * E_DIM + c1s),
          (void*)((char*)&Kl[buf][0] + dst1));
    gld16((const void*)(Vt + baset + (size_t)r0s * SEQ + k0 + c0s),
          (void*)((char*)&Vl[buf][0] + dst0));
    gld16((const void*)(Vt + baset + (size_t)r1s * SEQ + k0 + c1s),
          (void*)((char*)&Vl[buf][0] + dst1));
  };

  const int swz = (lq & 7) << 4;

  auto process = [&](f32x4 (&sv)[4], int qrow, bool diag, float& mreg,
                     f32x4 (&oacc)[4], f32x4& lacc, int kk0, s16x8 (&vf)[4][2]) {
#pragma unroll
    for (int kb = 0; kb < 4; ++kb)
#pragma unroll
      for (int r = 0; r < 4; ++r) {
        float v = sv[kb][r] * scale2;
        if (diag) {
          int kk = kk0 + kb * 16 + lg * 4 + r;
          if (kk > qrow) v = -1e30f;
        }
        sv[kb][r] = v;
      }
    float mx = sv[0][0];
#pragma unroll
    for (int kb = 0; kb < 4; ++kb)
#pragma unroll
      for (int r = 0; r < 4; ++r) mx = fmaxf(mx, sv[kb][r]);
    mx = fmaxf(mx, __shfl_xor(mx, 16, 64));
    mx = fmaxf(mx, __shfl_xor(mx, 32, 64));
    float mn = fmaxf(mreg, mx);
    float corr = __builtin_amdgcn_exp2f(mreg - mn);
    mreg = mn;
    unsigned c[4][2];
#pragma unroll
    for (int kb = 0; kb < 4; ++kb)
#pragma unroll
      for (int rp = 0; rp < 2; ++rp) {
        float plo = __builtin_amdgcn_exp2f(sv[kb][2 * rp] - mn);
        float phi = __builtin_amdgcn_exp2f(sv[kb][2 * rp + 1] - mn);
        c[kb][rp] = packbf2(plo, phi);
      }
#pragma unroll
    for (int k1 = 0; k1 < 2; ++k1)
#pragma unroll
      for (int rp = 0; rp < 2; ++rp) {
        unsigned a = c[2 * k1][rp], b = c[2 * k1 + 1][rp];
        unsigned x = hi5 ? a : b;
        x = __shfl_xor(x, 32, 64);
        c[2 * k1][rp] = hi5 ? x : a;
        c[2 * k1 + 1][rp] = hi5 ? b : x;
      }
#pragma unroll
    for (int k1 = 0; k1 < 2; ++k1)
#pragma unroll
      for (int rp = 0; rp < 2; ++rp) {
        unsigned a = c[2 * k1][rp], b = c[2 * k1 + 1][rp];
        unsigned x = hi4 ? a : b;
        x = __shfl_xor(x, 16, 64);
        c[2 * k1][rp] = hi4 ? x : a;
        c[2 * k1 + 1][rp] = hi4 ? b : x;
      }
#pragma unroll
    for (int db = 0; db < 4; ++db) oacc[db] = oacc[db] * corr;
    lacc = lacc * corr;
#pragma unroll
    for (int ks = 0; ks < 2; ++ks) {
      union { unsigned w[4]; s16x8 v; } pu;
      pu.w[0] = c[2 * ks][0]; pu.w[1] = c[2 * ks][1];
      pu.w[2] = c[2 * ks + 1][0]; pu.w[3] = c[2 * ks + 1][1];
      lacc = __builtin_amdgcn_mfma_f32_16x16x32_bf16(ones, pu.v, lacc, 0, 0, 0);
#pragma unroll
      for (int db = 0; db < 4; ++db)
        oacc[db] = __builtin_amdgcn_mfma_f32_16x16x32_bf16(vf[db][ks], pu.v, oacc[db], 0, 0, 0);
    }
  };

  stage(0, 0);
  __syncthreads();
  int cur = 0;

  for (int t = 0; t <= ntm1; ++t) {
    if (t < ntm1) stage(cur ^ 1, (t + 1) * 64);

    const char* Kc = (const char*)&Kl[cur][0];
    const char* Vc = (const char*)&Vl[cur][0];
    s16x8 kf[4][2];
#pragma unroll
    for (int kb = 0; kb < 4; ++kb)
#pragma unroll
      for (int j = 0; j < 2; ++j)
        kf[kb][j] = *(const s16x8*)(Kc + (((kb * 16 + lq) * 128 + j * 64 + lg * 16) ^ swz));
    s16x8 vf[4][2];
#pragma unroll
    for (int db = 0; db < 4; ++db)
#pragma unroll
      for (int ks = 0; ks < 2; ++ks)
        vf[db][ks] = *(const s16x8*)(Vc + (((db * 16 + lq) * 128 + ks * 64 + lg * 16) ^ swz));

    const int kk0 = t * 64;
    {
      f32x4 s1v[4] = {};
#pragma unroll
      for (int kb = 0; kb < 4; ++kb) {
        s1v[kb] = __builtin_amdgcn_mfma_f32_16x16x32_bf16(kf[kb][0], qf1[0], s1v[kb], 0, 0, 0);
        s1v[kb] = __builtin_amdgcn_mfma_f32_16x16x32_bf16(kf[kb][1], qf1[1], s1v[kb], 0, 0, 0);
      }
      process(s1v, row_hi, t == ntm1, m1r, o1, l1, kk0, vf);
    }
    if (t <= ip) {
      f32x4 s0v[4] = {};
#pragma unroll
      for (int kb = 0; kb < 4; ++kb) {
        s0v[kb] = __builtin_amdgcn_mfma_f32_16x16x32_bf16(kf[kb][0], qf0[0], s0v[kb], 0, 0, 0);
        s0v[kb] = __builtin_amdgcn_mfma_f32_16x16x32_bf16(kf[kb][1], qf0[1], s0v[kb], 0, 0, 0);
      }
      process(s0v, row_lo, t == ip, m0r, o0, l0, kk0, vf);
    }

    __syncthreads();
    cur ^= 1;
  }

  {
    float inv0 = 1.0f / l0[0], inv1 = 1.0f / l1[0];
#pragma unroll
    for (int db = 0; db < 4; ++db) {
      ushort4 w0, w1;
      w0.x = f2b(o0[db][0] * inv0); w0.y = f2b(o0[db][1] * inv0);
      w0.z = f2b(o0[db][2] * inv0); w0.w = f2b(o0[db][3] * inv0);
      w1.x = f2b(o1[db][0] * inv1); w1.y = f2b(o1[db][1] * inv1);
      w1.z = f2b(o1[db][2] * inv1); w1.w = f2b(o1[db][3] * inv1);
      *(ushort4*)&Ob[base + (size_t)row_lo * E_DIM + db * 16 + lg * 4] = w0;
      *(ushort4*)&Ob[base + (size_t)row_hi * E_DIM + db * 16 + lg * 4] = w1;
    }
  }
}

extern "C" void kernel_launch(void* const* d_in, const int* in_sizes, int n_in,
                              void* d_out, int out_size, void* d_ws, size_t ws_size,
                              hipStream_t stream) {
  const float* x    = (const float*)d_in[0];
  const float* wq_w = (const float*)d_in[1];
  const float* wq_b = (const float*)d_in[2];
  const float* wk_w = (const float*)d_in[3];
  const float* wk_b = (const float*)d_in[4];
  const float* wv_w = (const float*)d_in[5];
  const float* wv_b = (const float*)d_in[6];
  const float* wo_w = (const float*)d_in[7];
  const float* wo_b = (const float*)d_in[8];
  float* out = (float*)d_out;

  const size_t XE = (size_t)M_ROWS * E_DIM;
  const size_t WE = (size_t)E_DIM * E_DIM;
  char* ws = (char*)d_ws;
  unsigned short* xb    = (unsigned short*)ws; ws += XE * 2;
  unsigned short* wqkvT = (unsigned short*)ws; ws += 3 * WE * 2;  // [3072][1024]
  unsigned short* woT   = (unsigned short*)ws; ws += WE * 2;
  unsigned short* Qb    = (unsigned short*)ws; ws += XE * 2;
  unsigned short* Kb    = (unsigned short*)ws; ws += XE * 2;
  unsigned short* Vt    = (unsigned short*)ws; ws += XE * 2;  // [bh*64+d][s]
  unsigned short* Ao    = (unsigned short*)ws; ws += XE * 2;

  cast_x_kernel<<<2048, 256, 0, stream>>>(x, xb, (int)(XE / 4));
  wtrans4_kernel<<<dim3(E_DIM / 64, E_DIM / 64, 4), 256, 0, stream>>>(
      wq_w, wk_w, wv_w, wo_w, wqkvT, wqkvT + WE, wqkvT + 2 * WE, woT);

  gemm_qkv<<<dim3(M_ROWS / 128, 3072 / 128), 256, 0, stream>>>(
      xb, wqkvT, wq_b, wk_b, wv_b, Qb, Kb, Vt);

  attn6_kernel<<<1024, 256, 0, stream>>>(Qb, Kb, Vt, Ao);

  gemm_out<<<dim3(M_ROWS / 128, E_DIM / 128), 256, 0, stream>>>(Ao, woT, wo_b, out);
}

// Round 8
// 200.556 us; speedup vs baseline: 3.0308x; 1.0291x over previous
//
#include <hip/hip_runtime.h>
#include <hip/hip_bf16.h>

// Problem constants (CausalMultiHeadSelfAttention): B=4, S=2048, E=1024, H=16, D=64
#define E_DIM 1024
#define N_HEADS 16
#define HEAD_D 64
#define BATCH 4
#define SEQ 2048
#define M_ROWS (BATCH * SEQ)  // 8192
#define SCALE2 0.1803368801111244f  // 0.125 * log2(e): folded into Q at projection

typedef __attribute__((ext_vector_type(4))) float f32x4;
typedef __attribute__((ext_vector_type(8))) short s16x8;  // 8 bf16 in 4 VGPRs
typedef unsigned uint2v __attribute__((ext_vector_type(2)));

__device__ __forceinline__ unsigned short f2b(float f) {
  union { float f; unsigned u; } v; v.f = f;
  unsigned r = v.u + 0x7fffu + ((v.u >> 16) & 1u);  // RNE
  return (unsigned short)(r >> 16);
}

__device__ __forceinline__ unsigned packbf2(float lo, float hi) {
  union { __hip_bfloat162 h; unsigned u; } p;
  p.h = __float22bfloat162_rn(float2{lo, hi});  // v_cvt_pk_bf16_f32
  return p.u;
}

__device__ __forceinline__ void gld16(const void* g, void* l) {
  __builtin_amdgcn_global_load_lds(
      (__attribute__((address_space(1))) void*)(g),
      (__attribute__((address_space(3))) void*)(l), 16, 0, 0);
}

// lane-bit5 <-> reg swap (T12): single v_permlane32_swap_b32 when available
__device__ __forceinline__ void swap32(unsigned& a, unsigned& b, bool hi5) {
#if __has_builtin(__builtin_amdgcn_permlane32_swap)
  uint2v r = __builtin_amdgcn_permlane32_swap(a, b, false, false);
  a = r[0]; b = r[1];
#else
  unsigned x = hi5 ? a : b;
  x = __shfl_xor(x, 32, 64);
  unsigned na = hi5 ? x : a;
  b = hi5 ? b : x;
  a = na;
#endif
}
// lane-bit4 <-> reg swap: single v_permlane16_swap_b32 when available
__device__ __forceinline__ void swap16(unsigned& a, unsigned& b, bool hi4) {
#if __has_builtin(__builtin_amdgcn_permlane16_swap)
  uint2v r = __builtin_amdgcn_permlane16_swap(a, b, false, false);
  a = r[0]; b = r[1];
#else
  unsigned x = hi4 ? a : b;
  x = __shfl_xor(x, 16, 64);
  unsigned na = hi4 ? x : a;
  b = hi4 ? b : x;
  a = na;
#endif
}

// ---------------- cast x (fp32 -> bf16), vectorized ----------------
__global__ __launch_bounds__(256) void cast_x_kernel(const float* __restrict__ in,
                                                     unsigned short* __restrict__ out,
                                                     int n4) {
  int i = blockIdx.x * 256 + threadIdx.x;
  const int stride = gridDim.x * 256;
  for (; i < n4; i += stride) {
    float4 v = ((const float4*)in)[i];
    ushort4 o;
    o.x = f2b(v.x); o.y = f2b(v.y); o.z = f2b(v.z); o.w = f2b(v.w);
    ((ushort4*)out)[i] = o;
  }
}

// ------- fused weight transpose+cast: 4 weights in one launch (grid.z) -------
__global__ __launch_bounds__(256) void wtrans4_kernel(const float* __restrict__ W0,
                                                      const float* __restrict__ W1,
                                                      const float* __restrict__ W2,
                                                      const float* __restrict__ W3,
                                                      unsigned short* __restrict__ D0,
                                                      unsigned short* __restrict__ D1,
                                                      unsigned short* __restrict__ D2,
                                                      unsigned short* __restrict__ D3) {
  const int z = blockIdx.z;
  const float* W = (z == 0) ? W0 : (z == 1) ? W1 : (z == 2) ? W2 : W3;
  unsigned short* WT = (z == 0) ? D0 : (z == 1) ? D1 : (z == 2) ? D2 : D3;
  __shared__ float t[64][65];
  const int k0 = blockIdx.x * 64, n0 = blockIdx.y * 64;
  const int tid = threadIdx.x;
  const int rr = tid >> 4, cc = (tid & 15) * 4;
  for (int p = 0; p < 4; ++p) {
    int row = p * 16 + rr;
    float4 v = *(const float4*)&W[(size_t)(k0 + row) * E_DIM + n0 + cc];
    t[row][cc] = v.x; t[row][cc + 1] = v.y; t[row][cc + 2] = v.z; t[row][cc + 3] = v.w;
  }
  __syncthreads();
  for (int p = 0; p < 4; ++p) {
    int nrow = p * 16 + rr;
    ushort4 o;
    o.x = f2b(t[cc][nrow]); o.y = f2b(t[cc + 1][nrow]);
    o.z = f2b(t[cc + 2][nrow]); o.w = f2b(t[cc + 3][nrow]);
    *(ushort4*)&WT[(size_t)(n0 + nrow) * E_DIM + k0 + cc] = o;
  }
}

// ---------------- fused QKV GEMM: [8192,1024] x [1024,3072] ----------------
// Double-buffered LDS, issue-early staging, T2 XOR swizzle (round-7 schedule).
// NEW: Q output pre-scaled by SCALE2 (softmax scale folded out of attn).
__global__ __launch_bounds__(256) void gemm_qkv(const unsigned short* __restrict__ A,
                                                const unsigned short* __restrict__ BT,
                                                const float* __restrict__ bq,
                                                const float* __restrict__ bk,
                                                const float* __restrict__ bv,
                                                unsigned short* __restrict__ Qb,
                                                unsigned short* __restrict__ Kb,
                                                unsigned short* __restrict__ Vt) {
  __shared__ unsigned short Al[2][8192];
  __shared__ unsigned short Bl[2][8192];
  const int K = E_DIM;
  const int tid = threadIdx.x;
  const int lane = tid & 63;
  const int wave = tid >> 6;
  const int wr = wave >> 1, wc = wave & 1;
  const int m0 = blockIdx.x * 128, n0 = blockIdx.y * 128;
  const int lrow = lane & 15, lg = lane >> 4;

  f32x4 acc[4][4] = {};

  const int ob = tid << 4;
  const int dstb = (wave << 10);
  int srow[4], scol[4];
#pragma unroll
  for (int p = 0; p < 4; ++p) {
    int o = p * 4096 + ob;
    srow[p] = o >> 7;
    scol[p] = ((o ^ ((srow[p] & 7) << 4)) & 127) >> 1;
  }

  auto stage = [&](int buf, int k0) {
#pragma unroll
    for (int p = 0; p < 4; ++p) {
      gld16((const void*)(A + (size_t)(m0 + srow[p]) * K + k0 + scol[p]),
            (void*)((char*)&Al[buf][0] + p * 4096 + dstb));
      gld16((const void*)(BT + (size_t)(n0 + srow[p]) * K + k0 + scol[p]),
            (void*)((char*)&Bl[buf][0] + p * 4096 + dstb));
    }
  };

  const int swz = (lrow & 7) << 4;

  stage(0, 0);
  __syncthreads();
  int cur = 0;
  const int nt = K / 64;

  for (int t = 0; t < nt; ++t) {
    if (t + 1 < nt) stage(cur ^ 1, (t + 1) * 64);
    const char* Ac = (const char*)&Al[cur][0];
    const char* Bc = (const char*)&Bl[cur][0];
#pragma unroll
    for (int ks = 0; ks < 2; ++ks) {
      const int cb = ks * 64 + lg * 16;
      s16x8 af[4], bf_[4];
#pragma unroll
      for (int i = 0; i < 4; ++i)
        af[i] = *(const s16x8*)(Ac + (((wr * 64 + i * 16 + lrow) * 128 + cb) ^ swz));
#pragma unroll
      for (int j = 0; j < 4; ++j)
        bf_[j] = *(const s16x8*)(Bc + (((wc * 64 + j * 16 + lrow) * 128 + cb) ^ swz));
#pragma unroll
      for (int i = 0; i < 4; ++i)
#pragma unroll
        for (int j = 0; j < 4; ++j)
          acc[i][j] = __builtin_amdgcn_mfma_f32_16x16x32_bf16(af[i], bf_[j], acc[i][j], 0, 0, 0);
    }
    __syncthreads();
    cur ^= 1;
  }

  for (int j = 0; j < 4; ++j) {
    int c = n0 + wc * 64 + j * 16 + lrow;   // global col in [0,3072)
    int proj = c >> 10, cc = c & 1023;
    float bvl = (proj == 0) ? bq[cc] : (proj == 1) ? bk[cc] : bv[cc];
    for (int i = 0; i < 4; ++i) {
      int r0 = m0 + wr * 64 + i * 16 + (lg << 2);
      for (int r = 0; r < 4; ++r) {
        float val = acc[i][j][r] + bvl;
        int m = r0 + r;
        if (proj == 0) {
          Qb[(size_t)m * E_DIM + cc] = f2b(val * SCALE2);  // pre-scaled Q
        } else if (proj == 1) {
          Kb[(size_t)m * E_DIM + cc] = f2b(val);
        } else {
          int b = m >> 11, s = m & 2047;
          int h = cc >> 6, d = cc & 63;
          Vt[((size_t)((b * 16 + h) * 64 + d)) * SEQ + s] = f2b(val);
        }
      }
    }
  }
}

// ---------------- output projection GEMM (f32 out), same schedule ----------------
__global__ __launch_bounds__(256) void gemm_out(const unsigned short* __restrict__ A,
                                                const unsigned short* __restrict__ BT,
                                                const float* __restrict__ bias,
                                                float* __restrict__ C) {
  __shared__ unsigned short Al[2][8192];
  __shared__ unsigned short Bl[2][8192];
  const int K = E_DIM, N = E_DIM;
  const int tid = threadIdx.x;
  const int lane = tid & 63;
  const int wave = tid >> 6;
  const int wr = wave >> 1, wc = wave & 1;
  const int m0 = blockIdx.x * 128, n0 = blockIdx.y * 128;
  const int lrow = lane & 15, lg = lane >> 4;

  f32x4 acc[4][4] = {};

  const int ob = tid << 4;
  const int dstb = (wave << 10);
  int srow[4], scol[4];
#pragma unroll
  for (int p = 0; p < 4; ++p) {
    int o = p * 4096 + ob;
    srow[p] = o >> 7;
    scol[p] = ((o ^ ((srow[p] & 7) << 4)) & 127) >> 1;
  }

  auto stage = [&](int buf, int k0) {
#pragma unroll
    for (int p = 0; p < 4; ++p) {
      gld16((const void*)(A + (size_t)(m0 + srow[p]) * K + k0 + scol[p]),
            (void*)((char*)&Al[buf][0] + p * 4096 + dstb));
      gld16((const void*)(BT + (size_t)(n0 + srow[p]) * K + k0 + scol[p]),
            (void*)((char*)&Bl[buf][0] + p * 4096 + dstb));
    }
  };

  const int swz = (lrow & 7) << 4;

  stage(0, 0);
  __syncthreads();
  int cur = 0;
  const int nt = K / 64;

  for (int t = 0; t < nt; ++t) {
    if (t + 1 < nt) stage(cur ^ 1, (t + 1) * 64);
    const char* Ac = (const char*)&Al[cur][0];
    const char* Bc = (const char*)&Bl[cur][0];
#pragma unroll
    for (int ks = 0; ks < 2; ++ks) {
      const int cb = ks * 64 + lg * 16;
      s16x8 af[4], bf_[4];
#pragma unroll
      for (int i = 0; i < 4; ++i)
        af[i] = *(const s16x8*)(Ac + (((wr * 64 + i * 16 + lrow) * 128 + cb) ^ swz));
#pragma unroll
      for (int j = 0; j < 4; ++j)
        bf_[j] = *(const s16x8*)(Bc + (((wc * 64 + j * 16 + lrow) * 128 + cb) ^ swz));
#pragma unroll
      for (int i = 0; i < 4; ++i)
#pragma unroll
        for (int j = 0; j < 4; ++j)
          acc[i][j] = __builtin_amdgcn_mfma_f32_16x16x32_bf16(af[i], bf_[j], acc[i][j], 0, 0, 0);
    }
    __syncthreads();
    cur ^= 1;
  }

  for (int j = 0; j < 4; ++j) {
    int col = n0 + wc * 64 + j * 16 + lrow;
    float bvl = bias[col];
    for (int i = 0; i < 4; ++i) {
      int r0 = m0 + wr * 64 + i * 16 + (lg << 2);
      for (int r = 0; r < 4; ++r)
        C[(size_t)(r0 + r) * N + col] = acc[i][j][r] + bvl;
    }
  }
}

// ---------------- causal flash attention v7 (VALU diet) ----------------
// attn6 structure (LDS dbuf + swizzle + XCD locality) with:
//  - Q pre-scaled at projection -> no per-element scale pass (diag mask only)
//  - T12: permlane32/16_swap butterflies (8 instrs vs 16 ds_swizzle + 48 sel)
//  - T13: defer-rescale (skip corr-exp + 20 muls when __all(mx - m <= 8))
//  - depth-4 row-max tree
__global__ __launch_bounds__(256, 2) void attn7_kernel(const unsigned short* __restrict__ Qb,
                                                       const unsigned short* __restrict__ Kb,
                                                       const unsigned short* __restrict__ Vt,
                                                       unsigned short* __restrict__ Ob) {
  __shared__ unsigned short Kl[2][4096];
  __shared__ unsigned short Vl[2][4096];

  const int tid = threadIdx.x, lane = tid & 63, wave = tid >> 6;
  const int id = blockIdx.x;
  const int xcd = id & 7;
  const int slot = id >> 3;
  const int bh = (xcd << 3) | (slot >> 4);
  const int ip = slot & 15;
  const size_t base = (size_t)(bh >> 4) * SEQ * E_DIM + (size_t)(bh & 15) * HEAD_D;
  const size_t baset = (size_t)bh * HEAD_D * SEQ;
  const int lq = lane & 15, lg = lane >> 4;

  const int row_lo = ip * 64 + wave * 16 + lq;
  const int row_hi = (31 - ip) * 64 + wave * 16 + lq;

  s16x8 qf0[2], qf1[2];
  {
    const unsigned short* p0 = Qb + base + (size_t)row_lo * E_DIM + lg * 8;
    qf0[0] = *(const s16x8*)p0; qf0[1] = *(const s16x8*)(p0 + 32);
    const unsigned short* p1 = Qb + base + (size_t)row_hi * E_DIM + lg * 8;
    qf1[0] = *(const s16x8*)p1; qf1[1] = *(const s16x8*)(p1 + 32);
  }

  const short onebf = (short)0x3F80;
  const s16x8 ones = {onebf, onebf, onebf, onebf, onebf, onebf, onebf, onebf};

  float m0r = -1e30f, m1r = -1e30f;
  f32x4 o0[4] = {}, o1[4] = {};
  f32x4 l0 = {}, l1 = {};
  const int ntm1 = 31 - ip;
  const bool hi5 = (lane & 32) != 0, hi4 = (lane & 16) != 0;

  const int o0b = tid << 4;
  const int o1b = 4096 + (tid << 4);
  const int r0s = o0b >> 7, r1s = o1b >> 7;
  const int c0s = ((o0b ^ ((r0s & 7) << 4)) & 127) >> 1;
  const int c1s = ((o1b ^ ((r1s & 7) << 4)) & 127) >> 1;
  const int dst0 = wave << 10;
  const int dst1 = 4096 + (wave << 10);

  auto stage = [&](int buf, int k0) {
    gld16((const void*)(Kb + base + (size_t)(k0 + r0s) * E_DIM + c0s),
          (void*)((char*)&Kl[buf][0] + dst0));
    gld16((const void*)(Kb + base + (size_t)(k0 + r1s) * E_DIM + c1s),
          (void*)((char*)&Kl[buf][0] + dst1));
    gld16((const void*)(Vt + baset + (size_t)r0s * SEQ + k0 + c0s),
          (void*)((char*)&Vl[buf][0] + dst0));
    gld16((const void*)(Vt + baset + (size_t)r1s * SEQ + k0 + c1s),
          (void*)((char*)&Vl[buf][0] + dst1));
  };

  const int swz = (lq & 7) << 4;

  auto process = [&](f32x4 (&sv)[4], int qrow, bool diag, float& mreg,
                     f32x4 (&oacc)[4], f32x4& lacc, int kk0, s16x8 (&vf)[4][2]) {
    // causal mask only on the diagonal tile (Q pre-scaled at projection)
    if (diag) {
#pragma unroll
      for (int kb = 0; kb < 4; ++kb)
#pragma unroll
        for (int r = 0; r < 4; ++r) {
          int kk = kk0 + kb * 16 + lg * 4 + r;
          if (kk > qrow) sv[kb][r] = -1e30f;
        }
    }
    // row max: depth-4 tree + 2 cross-group shuffles
    float t0, t1, mk[4];
#pragma unroll
    for (int kb = 0; kb < 4; ++kb) {
      t0 = fmaxf(sv[kb][0], sv[kb][1]);
      t1 = fmaxf(sv[kb][2], sv[kb][3]);
      mk[kb] = fmaxf(t0, t1);
    }
    float mx = fmaxf(fmaxf(mk[0], mk[1]), fmaxf(mk[2], mk[3]));
    mx = fmaxf(mx, __shfl_xor(mx, 16, 64));
    mx = fmaxf(mx, __shfl_xor(mx, 32, 64));
    // T13 defer-rescale: skip when max growth <= 8 (exp2 domain -> P <= 256)
    if (!__all(mx - mreg <= 8.0f)) {
      float mn = fmaxf(mreg, mx);
      float corr = __builtin_amdgcn_exp2f(mreg - mn);
#pragma unroll
      for (int db = 0; db < 4; ++db) oacc[db] = oacc[db] * corr;
      lacc = lacc * corr;
      mreg = mn;
    }
    const float mn = mreg;
    unsigned c[4][2];
#pragma unroll
    for (int kb = 0; kb < 4; ++kb)
#pragma unroll
      for (int rp = 0; rp < 2; ++rp) {
        float plo = __builtin_amdgcn_exp2f(sv[kb][2 * rp] - mn);
        float phi = __builtin_amdgcn_exp2f(sv[kb][2 * rp + 1] - mn);
        c[kb][rp] = packbf2(plo, phi);
      }
    // butterfly B1 (lane-bit5 <-> reg kb0): v_permlane32_swap_b32
#pragma unroll
    for (int k1 = 0; k1 < 2; ++k1)
#pragma unroll
      for (int rp = 0; rp < 2; ++rp)
        swap32(c[2 * k1][rp], c[2 * k1 + 1][rp], hi5);
    // butterfly B2 (lane-bit4 <-> reg): v_permlane16_swap_b32
#pragma unroll
    for (int k1 = 0; k1 < 2; ++k1)
#pragma unroll
      for (int rp = 0; rp < 2; ++rp)
        swap16(c[2 * k1][rp], c[2 * k1 + 1][rp], hi4);
    // PV + row-sum
#pragma unroll
    for (int ks = 0; ks < 2; ++ks) {
      union { unsigned w[4]; s16x8 v; } pu;
      pu.w[0] = c[2 * ks][0]; pu.w[1] = c[2 * ks][1];
      pu.w[2] = c[2 * ks + 1][0]; pu.w[3] = c[2 * ks + 1][1];
      lacc = __builtin_amdgcn_mfma_f32_16x16x32_bf16(ones, pu.v, lacc, 0, 0, 0);
#pragma unroll
      for (int db = 0; db < 4; ++db)
        oacc[db] = __builtin_amdgcn_mfma_f32_16x16x32_bf16(vf[db][ks], pu.v, oacc[db], 0, 0, 0);
    }
  };

  stage(0, 0);
  __syncthreads();
  int cur = 0;

  for (int t = 0; t <= ntm1; ++t) {
    if (t < ntm1) stage(cur ^ 1, (t + 1) * 64);

    const char* Kc = (const char*)&Kl[cur][0];
    const char* Vc = (const char*)&Vl[cur][0];
    s16x8 kf[4][2];
#pragma unroll
    for (int kb = 0; kb < 4; ++kb)
#pragma unroll
      for (int j = 0; j < 2; ++j)
        kf[kb][j] = *(const s16x8*)(Kc + (((kb * 16 + lq) * 128 + j * 64 + lg * 16) ^ swz));
    s16x8 vf[4][2];
#pragma unroll
    for (int db = 0; db < 4; ++db)
#pragma unroll
      for (int ks = 0; ks < 2; ++ks)
        vf[db][ks] = *(const s16x8*)(Vc + (((db * 16 + lq) * 128 + ks * 64 + lg * 16) ^ swz));

    const int kk0 = t * 64;
    {
      f32x4 s1v[4] = {};
#pragma unroll
      for (int kb = 0; kb < 4; ++kb) {
        s1v[kb] = __builtin_amdgcn_mfma_f32_16x16x32_bf16(kf[kb][0], qf1[0], s1v[kb], 0, 0, 0);
        s1v[kb] = __builtin_amdgcn_mfma_f32_16x16x32_bf16(kf[kb][1], qf1[1], s1v[kb], 0, 0, 0);
      }
      process(s1v, row_hi, t == ntm1, m1r, o1, l1, kk0, vf);
    }
    if (t <= ip) {
      f32x4 s0v[4] = {};
#pragma unroll
      for (int kb = 0; kb < 4; ++kb) {
        s0v[kb] = __builtin_amdgcn_mfma_f32_16x16x32_bf16(kf[kb][0], qf0[0], s0v[kb], 0, 0, 0);
        s0v[kb] = __builtin_amdgcn_mfma_f32_16x16x32_bf16(kf[kb][1], qf0[1], s0v[kb], 0, 0, 0);
      }
      process(s0v, row_lo, t == ip, m0r, o0, l0, kk0, vf);
    }

    __syncthreads();
    cur ^= 1;
  }

  {
    float inv0 = 1.0f / l0[0], inv1 = 1.0f / l1[0];
#pragma unroll
    for (int db = 0; db < 4; ++db) {
      ushort4 w0, w1;
      w0.x = f2b(o0[db][0] * inv0); w0.y = f2b(o0[db][1] * inv0);
      w0.z = f2b(o0[db][2] * inv0); w0.w = f2b(o0[db][3] * inv0);
      w1.x = f2b(o1[db][0] * inv1); w1.y = f2b(o1[db][1] * inv1);
      w1.z = f2b(o1[db][2] * inv1); w1.w = f2b(o1[db][3] * inv1);
      *(ushort4*)&Ob[base + (size_t)row_lo * E_DIM + db * 16 + lg * 4] = w0;
      *(ushort4*)&Ob[base + (size_t)row_hi * E_DIM + db * 16 + lg * 4] = w1;
    }
  }
}

extern "C" void kernel_launch(void* const* d_in, const int* in_sizes, int n_in,
                              void* d_out, int out_size, void* d_ws, size_t ws_size,
                              hipStream_t stream) {
  const float* x    = (const float*)d_in[0];
  const float* wq_w = (const float*)d_in[1];
  const float* wq_b = (const float*)d_in[2];
  const float* wk_w = (const float*)d_in[3];
  const float* wk_b = (const float*)d_in[4];
  const float* wv_w = (const float*)d_in[5];
  const float* wv_b = (const float*)d_in[6];
  const float* wo_w = (const float*)d_in[7];
  const float* wo_b = (const float*)d_in[8];
  float* out = (float*)d_out;

  const size_t XE = (size_t)M_ROWS * E_DIM;
  const size_t WE = (size_t)E_DIM * E_DIM;
  char* ws = (char*)d_ws;
  unsigned short* xb    = (unsigned short*)ws; ws += XE * 2;
  unsigned short* wqkvT = (unsigned short*)ws; ws += 3 * WE * 2;  // [3072][1024]
  unsigned short* woT   = (unsigned short*)ws; ws += WE * 2;
  unsigned short* Qb    = (unsigned short*)ws; ws += XE * 2;
  unsigned short* Kb    = (unsigned short*)ws; ws += XE * 2;
  unsigned short* Vt    = (unsigned short*)ws; ws += XE * 2;  // [bh*64+d][s]
  unsigned short* Ao    = (unsigned short*)ws; ws += XE * 2;

  cast_x_kernel<<<2048, 256, 0, stream>>>(x, xb, (int)(XE / 4));
  wtrans4_kernel<<<dim3(E_DIM / 64, E_DIM / 64, 4), 256, 0, stream>>>(
      wq_w, wk_w, wv_w, wo_w, wqkvT, wqkvT + WE, wqkvT + 2 * WE, woT);

  gemm_qkv<<<dim3(M_ROWS / 128, 3072 / 128), 256, 0, stream>>>(
      xb, wqkvT, wq_b, wk_b, wv_b, Qb, Kb, Vt);

  attn7_kernel<<<1024, 256, 0, stream>>>(Qb, Kb, Vt, Ao);

  gemm_out<<<dim3(M_ROWS / 128, E_DIM / 128), 256, 0, stream>>>(Ao, woT, wo_b, out);
}